// Round 12
// baseline (162.292 us; speedup 1.0000x reference)
//
#include <hip/hip_runtime.h>
#include <math.h>

#define C_ 256
#define R_ 16
#define B_ 8
#define H_ 128
#define W_ 128
#define HW_ (H_ * W_)
#define CG_ 8            // channel groups
#define CPG_ (C_ / CG_)  // 32 channels per group
#define NCHUNK_ 16       // pixel chunks per image (1024 px each)

typedef float f4_ __attribute__((ext_vector_type(4)));

__device__ __forceinline__ float sigmoidf_(float z) {
    return 1.0f / (1.0f + __expf(-z));
}

__device__ __forceinline__ int reflect_(int g) {
    if (g < 0) g = -g;
    if (g > 127) g = 254 - g;
    return g;
}

// Single x-pass. Grid 1024 = (b, chunk, cg). Block reads 32 channels x 1024
// pixels (128 KiB) as float4. Stats via batched LDS partials; temp in regs.
__global__ void k1_stats_temp(const float* __restrict__ x, const float* __restrict__ dct_w,
                              float* __restrict__ ptemp,
                              float* __restrict__ psum, float* __restrict__ pmax) {
    __shared__ float sm_[CPG_];
    __shared__ float pmred[8][CPG_];
    __shared__ float ls[16][260];
    __shared__ float lm[16][260];
    int tid = threadIdx.x;
    int bid = blockIdx.x;
    int b = bid >> 7, chunk = (bid >> 3) & 15, cg = bid & 7;

    {   // m[c] slice for this channel group from L2-resident dct_w
        int c_l = tid & 31, oc = tid >> 5;
        const float* p = dct_w + cg * CPG_ + c_l;
        float pm = 0.0f;
        for (int k = 0; k < 32; ++k) pm += p[(oc * 32 + k) * C_];
        pmred[oc][c_l] = pm;
    }
    __syncthreads();
    if (tid < CPG_) {
        float t = 0.0f;
        for (int o = 0; o < 8; ++o) t += pmred[o][tid];
        sm_[tid] = t * (1.0f / C_);
    }
    __syncthreads();

    int pix = chunk * 1024 + tid * 4;
    const f4_* px = (const f4_*)(x + (size_t)(b * C_ + cg * CPG_) * HW_ + pix);
    int statbase = (b * NCHUNK_ + chunk) * C_ + cg * CPG_;

    f4_ acc = {0.0f, 0.0f, 0.0f, 0.0f};
    for (int half = 0; half < 2; ++half) {
        int c0 = half * 16;
#pragma unroll 8
        for (int cc = 0; cc < 16; ++cc) {
            int c = c0 + cc;
            f4_ v = px[(size_t)c * (HW_ / 4)];
            float w = sm_[c];
            acc.x = fmaf(w, v.x, acc.x);
            acc.y = fmaf(w, v.y, acc.y);
            acc.z = fmaf(w, v.z, acc.z);
            acc.w = fmaf(w, v.w, acc.w);
            ls[cc][tid] = (v.x + v.y) + (v.z + v.w);
            lm[cc][tid] = fmaxf(fmaxf(v.x, v.y), fmaxf(v.z, v.w));
        }
        __syncthreads();
        {
            int c_l = tid >> 4, s = tid & 15;
            float S = 0.0f, M = -3.402823466e+38f;
#pragma unroll
            for (int j = 0; j < 16; ++j) {
                S += ls[c_l][s + 16 * j];
                M = fmaxf(M, lm[c_l][s + 16 * j]);
            }
            for (int mo = 8; mo >= 1; mo >>= 1) {
                S += __shfl_xor(S, mo, 16);
                M = fmaxf(M, __shfl_xor(M, mo, 16));
            }
            if (s == 0) {
                psum[statbase + c0 + c_l] = S;
                pmax[statbase + c0 + c_l] = M;
            }
        }
        __syncthreads();
    }
    *(f4_*)(ptemp + (size_t)(cg * B_ + b) * HW_ + pix) = acc;
}

// Blocks 0..127: heat diffusion on 32x32 tiles, halo-3.
// Blocks 128..135: reduce stats partials -> SE MLP -> att.
#define TS_ 38
__global__ void k2_heat_fc(const float* __restrict__ ptemp,
                           const float* __restrict__ psum, const float* __restrict__ pmax,
                           const float* __restrict__ w1, const float* __restrict__ b1,
                           const float* __restrict__ w2, const float* __restrict__ b2,
                           const float* __restrict__ alphap, const float* __restrict__ lapp,
                           float* __restrict__ heat, float* __restrict__ att) {
    int tid = threadIdx.x;
    if (blockIdx.x < 128) {
        __shared__ float sA[TS_ * TS_], sB[TS_ * TS_];
        int b = blockIdx.x >> 4;
        int tile = blockIdx.x & 15;
        int tr = (tile >> 2) * 32, tc = (tile & 3) * 32;
        for (int i = tid; i < TS_ * TS_; i += 256) {
            int lh = i / TS_, lw = i % TS_;
            int gh = reflect_(tr + lh - 3);
            int gw = reflect_(tc + lw - 3);
            size_t a = (size_t)gh * W_ + gw + (size_t)b * HW_;
            float v = 0.0f;
#pragma unroll
            for (int cg = 0; cg < CG_; ++cg) v += ptemp[(size_t)cg * B_ * HW_ + a];
            sA[i] = v;
        }
        float alpha = *alphap;
        float l0 = lapp[0], l1 = lapp[1], l2 = lapp[2],
              l3 = lapp[3], l4 = lapp[4], l5 = lapp[5],
              l6 = lapp[6], l7 = lapp[7], l8 = lapp[8];
        __syncthreads();
#define DIFF(src, lh, lw)                                                              \
        fmaf(alpha,                                                                    \
             l0 * src[(lh - 1) * TS_ + lw - 1] + l1 * src[(lh - 1) * TS_ + lw] +       \
             l2 * src[(lh - 1) * TS_ + lw + 1] + l3 * src[lh * TS_ + lw - 1] +         \
             l4 * src[lh * TS_ + lw] + l5 * src[lh * TS_ + lw + 1] +                   \
             l6 * src[(lh + 1) * TS_ + lw - 1] + l7 * src[(lh + 1) * TS_ + lw] +       \
             l8 * src[(lh + 1) * TS_ + lw + 1],                                        \
             src[lh * TS_ + lw])
        for (int i = tid; i < 36 * 36; i += 256) {
            int lh = i / 36 + 1, lw = i % 36 + 1;
            sB[lh * TS_ + lw] = DIFF(sA, lh, lw);
        }
        __syncthreads();
        for (int i = tid; i < 34 * 34; i += 256) {
            int lh = i / 34 + 2, lw = i % 34 + 2;
            sA[lh * TS_ + lw] = DIFF(sB, lh, lw);
        }
        __syncthreads();
        float* hb = heat + b * HW_;
        for (int i = tid; i < 32 * 32; i += 256) {
            int lh = i / 32 + 3, lw = i % 32 + 3;
            float v = DIFF(sA, lh, lw);
            hb[(tr + lh - 3) * W_ + (tc + lw - 3)] = sigmoidf_(v);
        }
#undef DIFF
    } else {
        __shared__ float sa[C_], sx[C_], ha[R_], hm[R_];
        int b = blockIdx.x - 128;
        float S = 0.0f, M = -3.402823466e+38f;
        for (int ch = 0; ch < NCHUNK_; ++ch) {
            S += psum[(size_t)(b * NCHUNK_ + ch) * C_ + tid];
            M = fmaxf(M, pmax[(size_t)(b * NCHUNK_ + ch) * C_ + tid]);
        }
        sa[tid] = S * (1.0f / HW_);
        sx[tid] = M;
        __syncthreads();
        if (tid < 2 * R_) {
            int j = tid & (R_ - 1);
            bool isMax = tid >= R_;
            const float* y = isMax ? sx : sa;
            float s = b1[j];
            for (int c = 0; c < C_; ++c) s = fmaf(w1[j * C_ + c], y[c], s);
            s = fmaxf(s, 0.0f);
            (isMax ? hm : ha)[j] = s;
        }
        __syncthreads();
        float s1 = b2[tid], s2 = s1;
        for (int j = 0; j < R_; ++j) {
            float w = w2[tid * R_ + j];
            s1 = fmaf(w, ha[j], s1);
            s2 = fmaf(w, hm[j], s2);
        }
        att[b * C_ + tid] = sigmoidf_(s1) + sigmoidf_(s2);
    }
}

// out = x * sigmoid(att[b,c] * heat[b,hw]). Grid 4096, forward order.
// ATTRIBUTION PROBE: launched 3x (idempotent — same inputs, bitwise-same out).
// Delta over the 1x baseline = 2 x k3_warm (x and out L3-hot).
__global__ void k3_out(const float* __restrict__ x, const float* __restrict__ att,
                       const float* __restrict__ heat, float* __restrict__ out) {
    int bid = blockIdx.x;
    int bc = bid >> 1, half = bid & 1;
    int b = bc >> 8;
    float a = att[bc];
    size_t base = (size_t)bc * HW_ + half * (HW_ / 2);
    const f4_* px = (const f4_*)(x + base);
    const f4_* ph = (const f4_*)(heat + b * HW_ + half * (HW_ / 2));
    f4_* po = (f4_*)(out + base);
    int tid = threadIdx.x;
#pragma unroll
    for (int it = 0; it < HW_ / 8 / 256; ++it) {
        int i = it * 256 + tid;
        f4_ v = px[i];
        f4_ h = ph[i];
        f4_ r;
        r.x = v.x * sigmoidf_(a * h.x);
        r.y = v.y * sigmoidf_(a * h.y);
        r.z = v.z * sigmoidf_(a * h.z);
        r.w = v.w * sigmoidf_(a * h.w);
        po[i] = r;
    }
}

extern "C" void kernel_launch(void* const* d_in, const int* in_sizes, int n_in,
                              void* d_out, int out_size, void* d_ws, size_t ws_size,
                              hipStream_t stream) {
    const float* x     = (const float*)d_in[0];
    const float* dct_w = (const float*)d_in[1];
    const float* w1    = (const float*)d_in[2];
    const float* b1    = (const float*)d_in[3];
    const float* w2    = (const float*)d_in[4];
    const float* b2    = (const float*)d_in[5];
    const float* alpha = (const float*)d_in[6];
    const float* lap   = (const float*)d_in[7];
    float* out = (float*)d_out;

    float* ws    = (float*)d_ws;
    float* psum  = ws;                      // 8*16*256 = 32768
    float* pmax  = ws + 32768;              // 32768
    float* att   = ws + 65536;              // 2048
    float* heat  = ws + 69632;              // 131072
    float* ptemp = ws + 200704;             // 8*8*16384 = 1048576

    k1_stats_temp<<<1024, 256, 0, stream>>>(x, dct_w, ptemp, psum, pmax);
    k2_heat_fc<<<136, 256, 0, stream>>>(ptemp, psum, pmax, w1, b1, w2, b2, alpha, lap, heat, att);
    k3_out<<<4096, 256, 0, stream>>>(x, att, heat, out);
    k3_out<<<4096, 256, 0, stream>>>(x, att, heat, out);   // probe replica 1
    k3_out<<<4096, 256, 0, stream>>>(x, att, heat, out);   // probe replica 2
}

// Round 13
// 74.130 us; speedup vs baseline: 2.1893x; 2.1893x over previous
//
#include <hip/hip_runtime.h>
#include <math.h>

#define C_ 256
#define R_ 16
#define B_ 8
#define H_ 128
#define W_ 128
#define HW_ (H_ * W_)
#define CG_ 8            // channel groups
#define CPG_ (C_ / CG_)  // 32 channels per group
#define NCHUNK_ 16       // pixel chunks per image (1024 px each)

typedef float f4_ __attribute__((ext_vector_type(4)));

__device__ __forceinline__ float sigmoidf_(float z) {
    return 1.0f / (1.0f + __expf(-z));
}

__device__ __forceinline__ int reflect_(int g) {
    if (g < 0) g = -g;
    if (g > 127) g = 254 - g;
    return g;
}

// Single x-pass. Grid 1024 = (b, chunk, cg). Block reads 32 channels x 1024
// pixels (128 KiB) as float4. Stats via batched LDS partials; temp in regs.
// Measured ~24 us (134 MB HBM read @ ~5.6 TB/s).
__global__ void k1_stats_temp(const float* __restrict__ x, const float* __restrict__ dct_w,
                              float* __restrict__ ptemp,
                              float* __restrict__ psum, float* __restrict__ pmax) {
    __shared__ float sm_[CPG_];
    __shared__ float pmred[8][CPG_];
    __shared__ float ls[16][260];
    __shared__ float lm[16][260];
    int tid = threadIdx.x;
    int bid = blockIdx.x;
    int b = bid >> 7, chunk = (bid >> 3) & 15, cg = bid & 7;

    {   // m[c] slice for this channel group from L2-resident dct_w
        int c_l = tid & 31, oc = tid >> 5;
        const float* p = dct_w + cg * CPG_ + c_l;
        float pm = 0.0f;
        for (int k = 0; k < 32; ++k) pm += p[(oc * 32 + k) * C_];
        pmred[oc][c_l] = pm;
    }
    __syncthreads();
    if (tid < CPG_) {
        float t = 0.0f;
        for (int o = 0; o < 8; ++o) t += pmred[o][tid];
        sm_[tid] = t * (1.0f / C_);
    }
    __syncthreads();

    int pix = chunk * 1024 + tid * 4;
    const f4_* px = (const f4_*)(x + (size_t)(b * C_ + cg * CPG_) * HW_ + pix);
    int statbase = (b * NCHUNK_ + chunk) * C_ + cg * CPG_;

    f4_ acc = {0.0f, 0.0f, 0.0f, 0.0f};
    for (int half = 0; half < 2; ++half) {
        int c0 = half * 16;
#pragma unroll 8
        for (int cc = 0; cc < 16; ++cc) {
            int c = c0 + cc;
            f4_ v = px[(size_t)c * (HW_ / 4)];
            float w = sm_[c];
            acc.x = fmaf(w, v.x, acc.x);
            acc.y = fmaf(w, v.y, acc.y);
            acc.z = fmaf(w, v.z, acc.z);
            acc.w = fmaf(w, v.w, acc.w);
            ls[cc][tid] = (v.x + v.y) + (v.z + v.w);
            lm[cc][tid] = fmaxf(fmaxf(v.x, v.y), fmaxf(v.z, v.w));
        }
        __syncthreads();
        {
            int c_l = tid >> 4, s = tid & 15;
            float S = 0.0f, M = -3.402823466e+38f;
#pragma unroll
            for (int j = 0; j < 16; ++j) {
                S += ls[c_l][s + 16 * j];
                M = fmaxf(M, lm[c_l][s + 16 * j]);
            }
            for (int mo = 8; mo >= 1; mo >>= 1) {
                S += __shfl_xor(S, mo, 16);
                M = fmaxf(M, __shfl_xor(M, mo, 16));
            }
            if (s == 0) {
                psum[statbase + c0 + c_l] = S;
                pmax[statbase + c0 + c_l] = M;
            }
        }
        __syncthreads();
    }
    *(f4_*)(ptemp + (size_t)(cg * B_ + b) * HW_ + pix) = acc;
}

// Blocks 0..127: heat diffusion on 32x32 tiles, halo-3 (reflect + symmetric
// kernel => tile-local ghost compute exact). Blocks 128..135: stats -> SE MLP.
// Measured ~5.5 us (latency-bound, off the traffic path).
#define TS_ 38
__global__ void k2_heat_fc(const float* __restrict__ ptemp,
                           const float* __restrict__ psum, const float* __restrict__ pmax,
                           const float* __restrict__ w1, const float* __restrict__ b1,
                           const float* __restrict__ w2, const float* __restrict__ b2,
                           const float* __restrict__ alphap, const float* __restrict__ lapp,
                           float* __restrict__ heat, float* __restrict__ att) {
    int tid = threadIdx.x;
    if (blockIdx.x < 128) {
        __shared__ float sA[TS_ * TS_], sB[TS_ * TS_];
        int b = blockIdx.x >> 4;
        int tile = blockIdx.x & 15;
        int tr = (tile >> 2) * 32, tc = (tile & 3) * 32;
        for (int i = tid; i < TS_ * TS_; i += 256) {
            int lh = i / TS_, lw = i % TS_;
            int gh = reflect_(tr + lh - 3);
            int gw = reflect_(tc + lw - 3);
            size_t a = (size_t)gh * W_ + gw + (size_t)b * HW_;
            float v = 0.0f;
#pragma unroll
            for (int cg = 0; cg < CG_; ++cg) v += ptemp[(size_t)cg * B_ * HW_ + a];
            sA[i] = v;
        }
        float alpha = *alphap;
        float l0 = lapp[0], l1 = lapp[1], l2 = lapp[2],
              l3 = lapp[3], l4 = lapp[4], l5 = lapp[5],
              l6 = lapp[6], l7 = lapp[7], l8 = lapp[8];
        __syncthreads();
#define DIFF(src, lh, lw)                                                              \
        fmaf(alpha,                                                                    \
             l0 * src[(lh - 1) * TS_ + lw - 1] + l1 * src[(lh - 1) * TS_ + lw] +       \
             l2 * src[(lh - 1) * TS_ + lw + 1] + l3 * src[lh * TS_ + lw - 1] +         \
             l4 * src[lh * TS_ + lw] + l5 * src[lh * TS_ + lw + 1] +                   \
             l6 * src[(lh + 1) * TS_ + lw - 1] + l7 * src[(lh + 1) * TS_ + lw] +       \
             l8 * src[(lh + 1) * TS_ + lw + 1],                                        \
             src[lh * TS_ + lw])
        for (int i = tid; i < 36 * 36; i += 256) {
            int lh = i / 36 + 1, lw = i % 36 + 1;
            sB[lh * TS_ + lw] = DIFF(sA, lh, lw);
        }
        __syncthreads();
        for (int i = tid; i < 34 * 34; i += 256) {
            int lh = i / 34 + 2, lw = i % 34 + 2;
            sA[lh * TS_ + lw] = DIFF(sB, lh, lw);
        }
        __syncthreads();
        float* hb = heat + b * HW_;
        for (int i = tid; i < 32 * 32; i += 256) {
            int lh = i / 32 + 3, lw = i % 32 + 3;
            float v = DIFF(sA, lh, lw);
            hb[(tr + lh - 3) * W_ + (tc + lw - 3)] = sigmoidf_(v);
        }
#undef DIFF
    } else {
        __shared__ float sa[C_], sx[C_], ha[R_], hm[R_];
        int b = blockIdx.x - 128;
        float S = 0.0f, M = -3.402823466e+38f;
        for (int ch = 0; ch < NCHUNK_; ++ch) {
            S += psum[(size_t)(b * NCHUNK_ + ch) * C_ + tid];
            M = fmaxf(M, pmax[(size_t)(b * NCHUNK_ + ch) * C_ + tid]);
        }
        sa[tid] = S * (1.0f / HW_);
        sx[tid] = M;
        __syncthreads();
        if (tid < 2 * R_) {
            int j = tid & (R_ - 1);
            bool isMax = tid >= R_;
            const float* y = isMax ? sx : sa;
            float s = b1[j];
            for (int c = 0; c < C_; ++c) s = fmaf(w1[j * C_ + c], y[c], s);
            s = fmaxf(s, 0.0f);
            (isMax ? hm : ha)[j] = s;
        }
        __syncthreads();
        float s1 = b2[tid], s2 = s1;
        for (int j = 0; j < R_; ++j) {
            float w = w2[tid * R_ + j];
            s1 = fmaf(w, ha[j], s1);
            s2 = fmaf(w, hm[j], s2);
        }
        att[b * C_ + tid] = sigmoidf_(s1) + sigmoidf_(s2);
    }
}

// out = x * sigmoid(att[b,c] * heat[b,hw]). Grid 4096 (half-plane per block).
// Measured ~44 us warm or cold = 268 MB @ 6.1 TB/s = 97% of the float4-copy
// ceiling (6.29 TB/s) — at the mixed read+write roofline; L3 residency does
// not accelerate this stream (R12 probe).
__global__ void k3_out(const float* __restrict__ x, const float* __restrict__ att,
                       const float* __restrict__ heat, float* __restrict__ out) {
    int bid = blockIdx.x;
    int bc = bid >> 1, half = bid & 1;
    int b = bc >> 8;
    float a = att[bc];
    size_t base = (size_t)bc * HW_ + half * (HW_ / 2);
    const f4_* px = (const f4_*)(x + base);
    const f4_* ph = (const f4_*)(heat + b * HW_ + half * (HW_ / 2));
    f4_* po = (f4_*)(out + base);
    int tid = threadIdx.x;
#pragma unroll
    for (int it = 0; it < HW_ / 8 / 256; ++it) {
        int i = it * 256 + tid;
        f4_ v = px[i];
        f4_ h = ph[i];
        f4_ r;
        r.x = v.x * sigmoidf_(a * h.x);
        r.y = v.y * sigmoidf_(a * h.y);
        r.z = v.z * sigmoidf_(a * h.z);
        r.w = v.w * sigmoidf_(a * h.w);
        __builtin_nontemporal_store(r, &po[i]);
    }
}

extern "C" void kernel_launch(void* const* d_in, const int* in_sizes, int n_in,
                              void* d_out, int out_size, void* d_ws, size_t ws_size,
                              hipStream_t stream) {
    const float* x     = (const float*)d_in[0];
    const float* dct_w = (const float*)d_in[1];
    const float* w1    = (const float*)d_in[2];
    const float* b1    = (const float*)d_in[3];
    const float* w2    = (const float*)d_in[4];
    const float* b2    = (const float*)d_in[5];
    const float* alpha = (const float*)d_in[6];
    const float* lap   = (const float*)d_in[7];
    float* out = (float*)d_out;

    float* ws    = (float*)d_ws;
    float* psum  = ws;                      // 8*16*256 = 32768
    float* pmax  = ws + 32768;              // 32768
    float* att   = ws + 65536;              // 2048
    float* heat  = ws + 69632;              // 131072
    float* ptemp = ws + 200704;             // 8*8*16384 = 1048576

    k1_stats_temp<<<1024, 256, 0, stream>>>(x, dct_w, ptemp, psum, pmax);
    k2_heat_fc<<<136, 256, 0, stream>>>(ptemp, psum, pmax, w1, b1, w2, b2, alpha, lap, heat, att);
    k3_out<<<4096, 256, 0, stream>>>(x, att, heat, out);
}